// Round 1
// baseline (2029.783 us; speedup 1.0000x reference)
//
#include <hip/hip_runtime.h>
#include <cstdint>

#define HD 1024
#define INNER 2048
#define NTOK 2048
#define SEQL 1024
#define SDIM 16
#define DTR 64
#define VDIM 32000
#define FFN 2048
#define EPSV 1e-5f
#define SLOT_CAP 5120
#define MAX_TILES 40

typedef __attribute__((ext_vector_type(8))) short short8;
typedef __attribute__((ext_vector_type(4))) float f32x4;

__device__ __forceinline__ unsigned short f2bf(float f){
  unsigned int u = __float_as_uint(f);
  u += 0x7FFF + ((u >> 16) & 1);
  return (unsigned short)(u >> 16);
}
__device__ __forceinline__ float sigm(float x){ return 1.f/(1.f+__expf(-x)); }

__device__ __forceinline__ float block_sum(float v, float* sb){
  #pragma unroll
  for (int m=32;m>=1;m>>=1) v += __shfl_xor(v, m, 64);
  int lane = threadIdx.x & 63, w = threadIdx.x >> 6;
  if (lane==0) sb[w]=v;
  __syncthreads();
  float s = sb[0]+sb[1]+sb[2]+sb[3];
  __syncthreads();
  return s;
}

// ---------------- embed + rms0 ----------------
__global__ __launch_bounds__(256) void embed_rms_k(
  const int* __restrict__ ids, const float* __restrict__ emb,
  const float* __restrict__ n0w, float* __restrict__ x, float* __restrict__ xn)
{
  __shared__ float sb[4];
  int tok = blockIdx.x, t = threadIdx.x;
  int id = ids[tok];
  float4 v = *(const float4*)(emb + (size_t)id*HD + t*4);
  *(float4*)(x + (size_t)tok*HD + t*4) = v;
  float tot = block_sum(v.x*v.x+v.y*v.y+v.z*v.z+v.w*v.w, sb);
  float rs = rsqrtf(tot/(float)HD + EPSV);
  float4 w = *(const float4*)(n0w + t*4);
  float4 o; o.x=v.x*rs*w.x; o.y=v.y*rs*w.y; o.z=v.z*rs*w.z; o.w=v.w*rs*w.w;
  *(float4*)(xn + (size_t)tok*HD + t*4) = o;
}

// ---------------- generic fp32 GEMM: C[M,N] = A[M,K(lda)] * B[N,K]^T ----------------
// EPI 0: store. EPI 1: +bias then softplus. EPI 2: += C (residual in place)
template<int EPI>
__global__ __launch_bounds__(256) void gemm_f32k(
  const float* __restrict__ A, int lda,
  const float* __restrict__ B,
  float* __restrict__ C, int ldc,
  int N, int K, const float* __restrict__ bias)
{
  __shared__ float As[16][68];
  __shared__ float Bs[16][68];
  int m0 = blockIdx.y*64, n0 = blockIdx.x*64;
  int t = threadIdx.x, tm = t & 15, tn = t >> 4;
  float acc[4][4] = {};
  int srow = t >> 2, skq = (t & 3) * 4;
  const float* arow = A + (size_t)(m0 + srow)*lda + skq;
  int nrow = n0 + srow;
  const float* brow = B + (size_t)nrow*K + skq;
  bool bok = nrow < N;
  for (int k0 = 0; k0 < K; k0 += 16) {
    float4 a = *(const float4*)(arow + k0);
    float4 b = bok ? *(const float4*)(brow + k0) : make_float4(0.f,0.f,0.f,0.f);
    __syncthreads();
    As[skq+0][srow]=a.x; As[skq+1][srow]=a.y; As[skq+2][srow]=a.z; As[skq+3][srow]=a.w;
    Bs[skq+0][srow]=b.x; Bs[skq+1][srow]=b.y; Bs[skq+2][srow]=b.z; Bs[skq+3][srow]=b.w;
    __syncthreads();
    #pragma unroll
    for (int k=0;k<16;k++){
      const float4 av = *(const float4*)&As[k][tm*4];
      const float4 bv = *(const float4*)&Bs[k][tn*4];
      float am[4] = {av.x, av.y, av.z, av.w};
      float bn[4] = {bv.x, bv.y, bv.z, bv.w};
      #pragma unroll
      for (int i=0;i<4;i++)
        #pragma unroll
        for (int j=0;j<4;j++)
          acc[i][j] += am[i]*bn[j];
    }
  }
  #pragma unroll
  for (int i=0;i<4;i++){
    int row = m0 + tm*4 + i;
    #pragma unroll
    for (int j=0;j<4;j++){
      int col = n0 + tn*4 + j;
      if (col < N){
        float v = acc[i][j];
        if (EPI==1){ v += bias[col]; v = (v > 20.f) ? v : log1pf(expf(v)); }
        if (EPI==2){ v += C[(size_t)row*ldc + col]; }
        C[(size_t)row*ldc + col] = v;
      }
    }
  }
}

// ---------------- causal depthwise conv (K=4) + silu ----------------
__global__ __launch_bounds__(256) void conv_silu_k(
  const float* __restrict__ proj, const float* __restrict__ cw,
  const float* __restrict__ cb, float* __restrict__ uc)
{
  int idx = blockIdx.x*256 + threadIdx.x;     // over B*L*INNER
  int c = idx & (INNER-1);
  int l = (idx >> 11) & (SEQL-1);
  int b = idx >> 21;
  float s = cb[c];
  #pragma unroll
  for (int k=0;k<4;k++){
    int ll = l + k - 3;
    if (ll >= 0) s += proj[(size_t)(b*SEQL + ll)*4096 + c] * cw[c*4+k];
  }
  uc[idx] = s * sigm(s);
}

// ---------------- sequential selective scan ----------------
__global__ __launch_bounds__(256) void scan_k(
  const float* __restrict__ dl, const float* __restrict__ uc,
  const float* __restrict__ xp, const float* __restrict__ alog,
  const float* __restrict__ dpar, float* __restrict__ y)
{
  int c = (blockIdx.x & 7)*256 + threadIdx.x;
  int b = blockIdx.x >> 3;
  float a[SDIM];
  #pragma unroll
  for (int s=0;s<SDIM;s++) a[s] = -expf(alog[c*SDIM+s]);
  float st[SDIM] = {};
  float dv = dpar[c];
  size_t base = (size_t)b*SEQL;
  for (int l=0;l<SEQL;l++){
    size_t tix = base + l;
    float d = dl[tix*INNER + c];
    float u = uc[tix*INNER + c];
    const float* bc = xp + tix*96 + 64;
    float w = d*u, acc = 0.f;
    #pragma unroll
    for (int s=0;s<SDIM;s++){
      float p = __expf(d*a[s]);
      st[s] = p*st[s] + w*bc[s];
      acc += st[s]*bc[16+s];
    }
    y[tix*INNER + c] = acc + u*dv;
  }
}

// ---------------- y * silu(gate) ----------------
__global__ __launch_bounds__(256) void ygate_k(
  const float* __restrict__ y, const float* __restrict__ proj, float* __restrict__ yg)
{
  int idx = blockIdx.x*256 + threadIdx.x;
  int c = idx & (INNER-1); int t_ = idx >> 11;
  float g = proj[(size_t)t_*4096 + 2048 + c];
  yg[idx] = y[idx] * g * sigm(g);
}

// ---------------- rms1 + router (softmax top2) ----------------
__global__ __launch_bounds__(256) void rms_router_k(
  const float* __restrict__ x, const float* __restrict__ n1w,
  const float* __restrict__ rw, const float* __restrict__ rb,
  unsigned short* __restrict__ xnbf, int* __restrict__ ti, float* __restrict__ ts)
{
  __shared__ float sb[4];
  __shared__ float sb8[8][4];
  int tok = blockIdx.x, t = threadIdx.x;
  float4 v = *(const float4*)(x + (size_t)tok*HD + t*4);
  float tot = block_sum(v.x*v.x+v.y*v.y+v.z*v.z+v.w*v.w, sb);
  float rs = rsqrtf(tot/(float)HD + EPSV);
  float4 w = *(const float4*)(n1w + t*4);
  float4 xv; xv.x=v.x*rs*w.x; xv.y=v.y*rs*w.y; xv.z=v.z*rs*w.z; xv.w=v.w*rs*w.w;
  ushort4 o; o.x=f2bf(xv.x); o.y=f2bf(xv.y); o.z=f2bf(xv.z); o.w=f2bf(xv.w);
  *(ushort4*)(xnbf + (size_t)tok*HD + t*4) = o;
  float pe[8];
  #pragma unroll
  for (int e=0;e<8;e++){
    const float4 r4 = *(const float4*)(rw + (size_t)e*HD + t*4);
    pe[e] = xv.x*r4.x + xv.y*r4.y + xv.z*r4.z + xv.w*r4.w;
  }
  int lane = t & 63, wv = t >> 6;
  #pragma unroll
  for (int e=0;e<8;e++){
    float s = pe[e];
    #pragma unroll
    for (int m=32;m>=1;m>>=1) s += __shfl_xor(s, m, 64);
    if (lane==0) sb8[e][wv] = s;
  }
  __syncthreads();
  if (t==0){
    float lg[8], mx = -1e30f;
    for (int e=0;e<8;e++){ lg[e] = sb8[e][0]+sb8[e][1]+sb8[e][2]+sb8[e][3] + rb[e]; mx = fmaxf(mx, lg[e]); }
    float ex[8], sum=0.f;
    for (int e=0;e<8;e++){ ex[e]=expf(lg[e]-mx); sum+=ex[e]; }
    float inv = 1.f/sum;
    int i0=0; float p0=-1.f;
    for (int e=0;e<8;e++){ float p=ex[e]*inv; if (p>p0){p0=p;i0=e;} }
    int i1=-1; float p1=-1.f;
    for (int e=0;e<8;e++){ if (e==i0) continue; float p=ex[e]*inv; if (p>p1){p1=p;i1=e;} }
    ti[2*tok]=i0; ti[2*tok+1]=i1; ts[2*tok]=p0; ts[2*tok+1]=p1;
  }
}

// ---------------- routing: bucket tokens by expert into 128-padded tiles ----------------
__global__ void route_build_k(const int* __restrict__ ti, const float* __restrict__ ts,
  int* __restrict__ slot_token, int* __restrict__ tok_slots, int* __restrict__ tile_expert)
{
  __shared__ int cnt[8], cur[8];
  int t = threadIdx.x;
  if (t < 8) cnt[t] = 0;
  __syncthreads();
  for (int tok = t; tok < NTOK; tok += 256){
    atomicAdd(&cnt[ti[2*tok]], 1);
    atomicAdd(&cnt[ti[2*tok+1]], 1);
  }
  __syncthreads();
  if (t == 0){
    int off = 0, tile = 0;
    for (int e=0;e<8;e++){
      cur[e] = off;
      int nt2 = (cnt[e] + 127) >> 7;
      for (int j=0;j<nt2;j++) tile_expert[tile++] = e;
      off += nt2 << 7;
    }
    while (tile < MAX_TILES) tile_expert[tile++] = -1;
  }
  __syncthreads();
  for (int i = t; i < SLOT_CAP; i += 256) slot_token[i] = -1;
  __syncthreads();
  for (int tok = t; tok < NTOK; tok += 256){
    #pragma unroll
    for (int j=0;j<2;j++){
      int e = ti[2*tok+j];
      int p = atomicAdd(&cur[e], 1);
      slot_token[p] = tok;
      tok_slots[2*tok+j] = p;
    }
  }
}

// ---------------- bf16 MFMA GEMM: C[128-tile M, 128-tile N] = A(bf16)[*,K] * B(f32)[N,K]^T ----------------
template<bool GATHER, bool EXPERT>
__global__ __launch_bounds__(256) void gemm_bf16k(
  const unsigned short* __restrict__ A, int lda,
  const int* __restrict__ slot_token,
  const float* __restrict__ B0, long long expert_stride,
  const int* __restrict__ tile_expert,
  float* __restrict__ C, int ldc, int K)
{
  int mt = blockIdx.y, nt = blockIdx.x;
  const float* Bp = B0;
  if (EXPERT){
    int e = tile_expert[mt];
    if (e < 0) return;
    Bp = B0 + (long long)e * expert_stride;
  }
  int m0 = mt*128, n0 = nt*128;
  __shared__ unsigned short As[128][40];
  __shared__ unsigned short Bs[128][40];
  int t = threadIdx.x;
  int w = t >> 6, lane = t & 63;
  int wm = (w >> 1) * 64, wn = (w & 1) * 64;
  int lr = lane & 15, quad = lane >> 4;
  f32x4 acc[4][4] = {};

  int arow = t >> 1;
  int ahalf = t & 1;
  const unsigned short* asrc = nullptr;
  bool avalid = true;
  if (GATHER){
    int tok = slot_token[m0 + arow];
    avalid = (tok >= 0);
    if (avalid) asrc = A + (size_t)tok * lda;
  } else {
    asrc = A + (size_t)(m0 + arow) * lda;
  }
  const float* bsrc = Bp + (size_t)(n0 + arow) * K;

  for (int k0 = 0; k0 < K; k0 += 32){
    uint4 av0 = make_uint4(0,0,0,0), av1 = make_uint4(0,0,0,0);
    if (avalid){
      const uint4* p = (const uint4*)(asrc + k0 + ahalf*16);
      av0 = p[0]; av1 = p[1];
    }
    const float4* q = (const float4*)(bsrc + k0 + ahalf*16);
    float4 b0 = q[0], b1 = q[1], b2 = q[2], b3 = q[3];
    uint4 w0, w1;
    w0.x = (uint32_t)f2bf(b0.x) | ((uint32_t)f2bf(b0.y)<<16);
    w0.y = (uint32_t)f2bf(b0.z) | ((uint32_t)f2bf(b0.w)<<16);
    w0.z = (uint32_t)f2bf(b1.x) | ((uint32_t)f2bf(b1.y)<<16);
    w0.w = (uint32_t)f2bf(b1.z) | ((uint32_t)f2bf(b1.w)<<16);
    w1.x = (uint32_t)f2bf(b2.x) | ((uint32_t)f2bf(b2.y)<<16);
    w1.y = (uint32_t)f2bf(b2.z) | ((uint32_t)f2bf(b2.w)<<16);
    w1.z = (uint32_t)f2bf(b3.x) | ((uint32_t)f2bf(b3.y)<<16);
    w1.w = (uint32_t)f2bf(b3.z) | ((uint32_t)f2bf(b3.w)<<16);
    __syncthreads();
    *(uint4*)&As[arow][ahalf*16]     = av0;
    *(uint4*)&As[arow][ahalf*16 + 8] = av1;
    *(uint4*)&Bs[arow][ahalf*16]     = w0;
    *(uint4*)&Bs[arow][ahalf*16 + 8] = w1;
    __syncthreads();
    short8 af[4], bf[4];
    #pragma unroll
    for (int mi=0;mi<4;mi++) af[mi] = *(const short8*)&As[wm + mi*16 + lr][quad*8];
    #pragma unroll
    for (int ni=0;ni<4;ni++) bf[ni] = *(const short8*)&Bs[wn + ni*16 + lr][quad*8];
    #pragma unroll
    for (int mi=0;mi<4;mi++)
      #pragma unroll
      for (int ni=0;ni<4;ni++)
        acc[mi][ni] = __builtin_amdgcn_mfma_f32_16x16x32_bf16(af[mi], bf[ni], acc[mi][ni], 0, 0, 0);
  }
  #pragma unroll
  for (int mi=0;mi<4;mi++){
    int rbase = m0 + wm + mi*16 + quad*4;
    #pragma unroll
    for (int ni=0;ni<4;ni++){
      int col = n0 + wn + ni*16 + lr;
      float* cp = C + (size_t)rbase*ldc + col;
      #pragma unroll
      for (int r=0;r<4;r++) cp[(size_t)r*ldc] = acc[mi][ni][r];
    }
  }
}

// ---------------- silu(h1a)*h1b -> hidden bf16 ----------------
__global__ __launch_bounds__(256) void silu_mul_k(
  const float* __restrict__ h1, unsigned short* __restrict__ hidden)
{
  int idx = blockIdx.x*256 + threadIdx.x;   // over SLOT_CAP*FFN
  int f = idx & (FFN-1); int slot = idx >> 11;
  float a = h1[(size_t)slot*2*FFN + f];
  float b = h1[(size_t)slot*2*FFN + FFN + f];
  hidden[idx] = f2bf(a*sigm(a)*b);
}

// ---------------- combine experts + final rms -> xnf bf16 ----------------
__global__ __launch_bounds__(256) void combine_rms_k(
  const float* __restrict__ x, const float* __restrict__ eo,
  const int* __restrict__ tok_slots, const float* __restrict__ ts,
  const float* __restrict__ fw, unsigned short* __restrict__ xnf)
{
  __shared__ float sb[4];
  int tok = blockIdx.x, t = threadIdx.x;
  int p0 = tok_slots[2*tok], p1 = tok_slots[2*tok+1];
  float s0 = ts[2*tok], s1 = ts[2*tok+1];
  float4 v  = *(const float4*)(x  + (size_t)tok*HD + t*4);
  float4 e0 = *(const float4*)(eo + (size_t)p0*HD + t*4);
  float4 e1 = *(const float4*)(eo + (size_t)p1*HD + t*4);
  v.x += s0*e0.x + s1*e1.x;
  v.y += s0*e0.y + s1*e1.y;
  v.z += s0*e0.z + s1*e1.z;
  v.w += s0*e0.w + s1*e1.w;
  float tot = block_sum(v.x*v.x+v.y*v.y+v.z*v.z+v.w*v.w, sb);
  float rs = rsqrtf(tot/(float)HD + EPSV);
  float4 w = *(const float4*)(fw + t*4);
  ushort4 o;
  o.x=f2bf(v.x*rs*w.x); o.y=f2bf(v.y*rs*w.y); o.z=f2bf(v.z*rs*w.z); o.w=f2bf(v.w*rs*w.w);
  *(ushort4*)(xnf + (size_t)tok*HD + t*4) = o;
}

extern "C" void kernel_launch(void* const* d_in, const int* in_sizes, int n_in,
                              void* d_out, int out_size, void* d_ws, size_t ws_size,
                              hipStream_t stream)
{
  const int*   ids  = (const int*)  d_in[0];
  const float* emb  = (const float*)d_in[1];
  const float* n0w  = (const float*)d_in[2];
  const float* ipw  = (const float*)d_in[3];
  const float* cw   = (const float*)d_in[4];
  const float* cb   = (const float*)d_in[5];
  const float* xpw  = (const float*)d_in[6];
  const float* dtw  = (const float*)d_in[7];
  const float* dtb  = (const float*)d_in[8];
  const float* alog = (const float*)d_in[9];
  const float* dpar = (const float*)d_in[10];
  const float* opw  = (const float*)d_in[11];
  const float* n1w  = (const float*)d_in[12];
  const float* rw   = (const float*)d_in[13];
  const float* rb   = (const float*)d_in[14];
  const float* f1w  = (const float*)d_in[15];
  const float* f2w  = (const float*)d_in[16];
  const float* fnw  = (const float*)d_in[17];
  float* out = (float*)d_out;
  char* ws = (char*)d_ws;

  // workspace layout (bytes); h1 overlays the dead proj..y span
  size_t o_x       = 0;                          // 8,388,608
  size_t o_xnbf    = o_x + 8388608;              // 4,194,304
  size_t o_ti      = o_xnbf + 4194304;           // 16,384
  size_t o_ts      = o_ti + 16384;               // 16,384
  size_t o_slott   = o_ts + 16384;               // 20,480
  size_t o_tslots  = o_slott + 20480;            // 16,384
  size_t o_tile    = o_tslots + 16384;           // 256
  size_t o_xn      = o_tile + 256;               // 8,388,608
  size_t o_proj    = o_xn + 8388608;             // 33,554,432
  size_t o_uconv   = o_proj + 33554432;          // 16,777,216
  size_t o_xp      = o_uconv + 16777216;         // 786,432
  size_t o_dl      = o_xp + 786432;              // 16,777,216
  size_t o_y       = o_dl + 16777216;            // 16,777,216
  size_t o_yg      = o_y + 16777216;             // 16,777,216
  size_t o_h1      = o_proj;                     // 83,886,080 (overlay, fits in proj..y span)
  size_t o_hidden  = o_yg + 16777216;            // 20,971,520
  size_t o_eo      = o_hidden + 20971520;        // 20,971,520
  size_t o_xnf     = o_eo + 20971520;            // 4,194,304

  float* x      = (float*)(ws + o_x);
  unsigned short* xnbf = (unsigned short*)(ws + o_xnbf);
  int*   ti     = (int*)(ws + o_ti);
  float* ts     = (float*)(ws + o_ts);
  int*   slott  = (int*)(ws + o_slott);
  int*   tslots = (int*)(ws + o_tslots);
  int*   tile_e = (int*)(ws + o_tile);
  float* xn     = (float*)(ws + o_xn);
  float* proj   = (float*)(ws + o_proj);
  float* uconv  = (float*)(ws + o_uconv);
  float* xp     = (float*)(ws + o_xp);
  float* dl     = (float*)(ws + o_dl);
  float* y      = (float*)(ws + o_y);
  float* yg     = (float*)(ws + o_yg);
  float* h1     = (float*)(ws + o_h1);
  unsigned short* hidden = (unsigned short*)(ws + o_hidden);
  float* eo     = (float*)(ws + o_eo);
  unsigned short* xnf = (unsigned short*)(ws + o_xnf);

  embed_rms_k<<<NTOK,256,0,stream>>>(ids, emb, n0w, x, xn);
  // in_proj: [2048,1024] x [4096,1024]^T -> proj [2048,4096]
  gemm_f32k<0><<<dim3(64,32),256,0,stream>>>(xn, HD, ipw, proj, 4096, 4096, HD, nullptr);
  conv_silu_k<<<(NTOK*INNER)/256,256,0,stream>>>(proj, cw, cb, uconv);
  // x_proj: [2048,2048] x [96,2048]^T -> xp [2048,96]
  gemm_f32k<0><<<dim3(2,32),256,0,stream>>>(uconv, INNER, xpw, xp, 96, 96, INNER, nullptr);
  // dt_proj + bias + softplus: [2048,64(of 96)] x [2048,64]^T -> dl [2048,2048]
  gemm_f32k<1><<<dim3(32,32),256,0,stream>>>(xp, 96, dtw, dl, INNER, INNER, DTR, dtb);
  scan_k<<<16,256,0,stream>>>(dl, uconv, xp, alog, dpar, y);
  ygate_k<<<(NTOK*INNER)/256,256,0,stream>>>(y, proj, yg);
  // out_proj + residual: [2048,2048] x [1024,2048]^T -> x += ...
  gemm_f32k<2><<<dim3(16,32),256,0,stream>>>(yg, INNER, opw, x, HD, HD, INNER, nullptr);
  rms_router_k<<<NTOK,256,0,stream>>>(x, n1w, rw, rb, xnbf, ti, ts);
  route_build_k<<<1,256,0,stream>>>(ti, ts, slott, tslots, tile_e);
  // fc1: gathered xn (bf16) x fc1_w[e] -> h1 [5120,4096]
  gemm_bf16k<true,true><<<dim3(32,MAX_TILES),256,0,stream>>>(
      xnbf, HD, slott, f1w, 4096LL*1024LL, tile_e, h1, 4096, HD);
  silu_mul_k<<<(SLOT_CAP*FFN)/256,256,0,stream>>>(h1, hidden);
  // fc2: hidden (bf16) x fc2_w[e] -> eo [5120,1024]
  gemm_bf16k<false,true><<<dim3(8,MAX_TILES),256,0,stream>>>(
      hidden, FFN, nullptr, f2w, 1024LL*2048LL, tile_e, eo, HD, FFN);
  combine_rms_k<<<NTOK,256,0,stream>>>(x, eo, tslots, ts, fnw, xnf);
  // LM head: xnf (bf16) x emb -> out [2048,32000]
  gemm_bf16k<false,false><<<dim3(VDIM/128,NTOK/128),256,0,stream>>>(
      xnf, HD, nullptr, emb, 0LL, nullptr, out, VDIM, HD);
}

// Round 2
// 1539.234 us; speedup vs baseline: 1.3187x; 1.3187x over previous
//
#include <hip/hip_runtime.h>
#include <cstdint>

#define HD 1024
#define INNER 2048
#define NTOK 2048
#define SEQL 1024
#define SDIM 16
#define DTR 64
#define VDIM 32000
#define FFN 2048
#define EPSV 1e-5f
#define SLOT_CAP 5120
#define MAX_TILES 40
#define NCH 32
#define CLEN 32

typedef __attribute__((ext_vector_type(8))) short short8;
typedef __attribute__((ext_vector_type(4))) float f32x4;

__device__ __forceinline__ unsigned short f2bf(float f){
  unsigned int u = __float_as_uint(f);
  u += 0x7FFF + ((u >> 16) & 1);
  return (unsigned short)(u >> 16);
}
__device__ __forceinline__ float sigm(float x){ return 1.f/(1.f+__expf(-x)); }

__device__ __forceinline__ float block_sum(float v, float* sb){
  #pragma unroll
  for (int m=32;m>=1;m>>=1) v += __shfl_xor(v, m, 64);
  int lane = threadIdx.x & 63, w = threadIdx.x >> 6;
  if (lane==0) sb[w]=v;
  __syncthreads();
  float s = sb[0]+sb[1]+sb[2]+sb[3];
  __syncthreads();
  return s;
}

// ---------------- embed + rms0 ----------------
__global__ __launch_bounds__(256) void embed_rms_k(
  const int* __restrict__ ids, const float* __restrict__ emb,
  const float* __restrict__ n0w, float* __restrict__ x, float* __restrict__ xn)
{
  __shared__ float sb[4];
  int tok = blockIdx.x, t = threadIdx.x;
  int id = ids[tok];
  float4 v = *(const float4*)(emb + (size_t)id*HD + t*4);
  *(float4*)(x + (size_t)tok*HD + t*4) = v;
  float tot = block_sum(v.x*v.x+v.y*v.y+v.z*v.z+v.w*v.w, sb);
  float rs = rsqrtf(tot/(float)HD + EPSV);
  float4 w = *(const float4*)(n0w + t*4);
  float4 o; o.x=v.x*rs*w.x; o.y=v.y*rs*w.y; o.z=v.z*rs*w.z; o.w=v.w*rs*w.w;
  *(float4*)(xn + (size_t)tok*HD + t*4) = o;
}

// ---------------- generic fp32 GEMM: C[M,N] = A[M,K(lda)] * B[N,K]^T ----------------
// EPI 0: store. EPI 1: +bias then softplus. EPI 2: += C (residual in place)
template<int EPI>
__global__ __launch_bounds__(256) void gemm_f32k(
  const float* __restrict__ A, int lda,
  const float* __restrict__ B,
  float* __restrict__ C, int ldc,
  int N, int K, const float* __restrict__ bias)
{
  __shared__ float As[16][68];
  __shared__ float Bs[16][68];
  int m0 = blockIdx.y*64, n0 = blockIdx.x*64;
  int t = threadIdx.x, tm = t & 15, tn = t >> 4;
  float acc[4][4] = {};
  int srow = t >> 2, skq = (t & 3) * 4;
  const float* arow = A + (size_t)(m0 + srow)*lda + skq;
  int nrow = n0 + srow;
  const float* brow = B + (size_t)nrow*K + skq;
  bool bok = nrow < N;
  for (int k0 = 0; k0 < K; k0 += 16) {
    float4 a = *(const float4*)(arow + k0);
    float4 b = bok ? *(const float4*)(brow + k0) : make_float4(0.f,0.f,0.f,0.f);
    __syncthreads();
    As[skq+0][srow]=a.x; As[skq+1][srow]=a.y; As[skq+2][srow]=a.z; As[skq+3][srow]=a.w;
    Bs[skq+0][srow]=b.x; Bs[skq+1][srow]=b.y; Bs[skq+2][srow]=b.z; Bs[skq+3][srow]=b.w;
    __syncthreads();
    #pragma unroll
    for (int k=0;k<16;k++){
      const float4 av = *(const float4*)&As[k][tm*4];
      const float4 bv = *(const float4*)&Bs[k][tn*4];
      float am[4] = {av.x, av.y, av.z, av.w};
      float bn[4] = {bv.x, bv.y, bv.z, bv.w};
      #pragma unroll
      for (int i=0;i<4;i++)
        #pragma unroll
        for (int j=0;j<4;j++)
          acc[i][j] += am[i]*bn[j];
    }
  }
  #pragma unroll
  for (int i=0;i<4;i++){
    int row = m0 + tm*4 + i;
    #pragma unroll
    for (int j=0;j<4;j++){
      int col = n0 + tn*4 + j;
      if (col < N){
        float v = acc[i][j];
        if (EPI==1){ v += bias[col]; v = (v > 20.f) ? v : log1pf(expf(v)); }
        if (EPI==2){ v += C[(size_t)row*ldc + col]; }
        C[(size_t)row*ldc + col] = v;
      }
    }
  }
}

// ---------------- causal depthwise conv (K=4) + silu ----------------
__global__ __launch_bounds__(256) void conv_silu_k(
  const float* __restrict__ proj, const float* __restrict__ cw,
  const float* __restrict__ cb, float* __restrict__ uc)
{
  int idx = blockIdx.x*256 + threadIdx.x;     // over B*L*INNER
  int c = idx & (INNER-1);
  int l = (idx >> 11) & (SEQL-1);
  int b = idx >> 21;
  float s = cb[c];
  #pragma unroll
  for (int k=0;k<4;k++){
    int ll = l + k - 3;
    if (ll >= 0) s += proj[(size_t)(b*SEQL + ll)*4096 + c] * cw[c*4+k];
  }
  uc[idx] = s * sigm(s);
}

// ---------------- chunked selective scan: pass 1 (local states + decay products) ----------------
__global__ __launch_bounds__(256) void scan_p1(
  const float* __restrict__ dl, const float* __restrict__ uc,
  const float* __restrict__ xp, const float* __restrict__ alog,
  float* __restrict__ locfin, float* __restrict__ Pst)
{
  int c = blockIdx.x*256 + threadIdx.x;
  int chunk = blockIdx.y, b = blockIdx.z;
  float a[SDIM];
  #pragma unroll
  for (int s=0;s<SDIM;s++) a[s] = -expf(alog[c*SDIM+s]);
  float st[SDIM] = {};
  float P[SDIM];
  #pragma unroll
  for (int s=0;s<SDIM;s++) P[s] = 1.f;
  size_t base = (size_t)b*SEQL + chunk*CLEN;
  #pragma unroll 2
  for (int l=0;l<CLEN;l++){
    size_t tix = base + l;
    float d = dl[tix*INNER + c];
    float u = uc[tix*INNER + c];
    const float* bc = xp + tix*96 + 64;
    float w = d*u;
    #pragma unroll
    for (int s=0;s<SDIM;s++){
      float p = __expf(d*a[s]);
      st[s] = p*st[s] + w*bc[s];
      P[s] *= p;
    }
  }
  size_t cb = (size_t)(b*NCH + chunk)*SDIM*INNER + c;
  #pragma unroll
  for (int s=0;s<SDIM;s++){
    locfin[cb + (size_t)s*INNER] = st[s];
    Pst[cb + (size_t)s*INNER] = P[s];
  }
}

// ---------------- pass 2: scan over chunk summaries (parallel over chain x state) ----------------
__global__ __launch_bounds__(256) void scan_p2(
  const float* __restrict__ locfin, const float* __restrict__ Pst,
  float* __restrict__ initst)
{
  int c = blockIdx.x*256 + threadIdx.x;
  int s = blockIdx.y, b = blockIdx.z;
  float carry = 0.f;
  #pragma unroll 4
  for (int chunk=0; chunk<NCH; chunk++){
    size_t idx = ((size_t)(b*NCH + chunk)*SDIM + s)*INNER + c;
    initst[idx] = carry;
    carry = Pst[idx]*carry + locfin[idx];
  }
}

// ---------------- pass 3: replay with true init state, emit y ----------------
__global__ __launch_bounds__(256) void scan_p3(
  const float* __restrict__ dl, const float* __restrict__ uc,
  const float* __restrict__ xp, const float* __restrict__ alog,
  const float* __restrict__ dpar, const float* __restrict__ initst,
  float* __restrict__ y)
{
  int c = blockIdx.x*256 + threadIdx.x;
  int chunk = blockIdx.y, b = blockIdx.z;
  float a[SDIM], st[SDIM];
  #pragma unroll
  for (int s=0;s<SDIM;s++) a[s] = -expf(alog[c*SDIM+s]);
  size_t cb = (size_t)(b*NCH + chunk)*SDIM*INNER + c;
  #pragma unroll
  for (int s=0;s<SDIM;s++) st[s] = initst[cb + (size_t)s*INNER];
  float dv = dpar[c];
  size_t base = (size_t)b*SEQL + chunk*CLEN;
  #pragma unroll 2
  for (int l=0;l<CLEN;l++){
    size_t tix = base + l;
    float d = dl[tix*INNER + c];
    float u = uc[tix*INNER + c];
    const float* bc = xp + tix*96 + 64;
    float w = d*u, acc = 0.f;
    #pragma unroll
    for (int s=0;s<SDIM;s++){
      float p = __expf(d*a[s]);
      st[s] = p*st[s] + w*bc[s];
      acc += st[s]*bc[16+s];
    }
    y[tix*INNER + c] = acc + u*dv;
  }
}

// ---------------- y * silu(gate) ----------------
__global__ __launch_bounds__(256) void ygate_k(
  const float* __restrict__ y, const float* __restrict__ proj, float* __restrict__ yg)
{
  int idx = blockIdx.x*256 + threadIdx.x;
  int c = idx & (INNER-1); int t_ = idx >> 11;
  float g = proj[(size_t)t_*4096 + 2048 + c];
  yg[idx] = y[idx] * g * sigm(g);
}

// ---------------- rms1 + router (softmax top2) ----------------
__global__ __launch_bounds__(256) void rms_router_k(
  const float* __restrict__ x, const float* __restrict__ n1w,
  const float* __restrict__ rw, const float* __restrict__ rb,
  unsigned short* __restrict__ xnbf, int* __restrict__ ti, float* __restrict__ ts)
{
  __shared__ float sb[4];
  __shared__ float sb8[8][4];
  int tok = blockIdx.x, t = threadIdx.x;
  float4 v = *(const float4*)(x + (size_t)tok*HD + t*4);
  float tot = block_sum(v.x*v.x+v.y*v.y+v.z*v.z+v.w*v.w, sb);
  float rs = rsqrtf(tot/(float)HD + EPSV);
  float4 w = *(const float4*)(n1w + t*4);
  float4 xv; xv.x=v.x*rs*w.x; xv.y=v.y*rs*w.y; xv.z=v.z*rs*w.z; xv.w=v.w*rs*w.w;
  ushort4 o; o.x=f2bf(xv.x); o.y=f2bf(xv.y); o.z=f2bf(xv.z); o.w=f2bf(xv.w);
  *(ushort4*)(xnbf + (size_t)tok*HD + t*4) = o;
  float pe[8];
  #pragma unroll
  for (int e=0;e<8;e++){
    const float4 r4 = *(const float4*)(rw + (size_t)e*HD + t*4);
    pe[e] = xv.x*r4.x + xv.y*r4.y + xv.z*r4.z + xv.w*r4.w;
  }
  int lane = t & 63, wv = t >> 6;
  #pragma unroll
  for (int e=0;e<8;e++){
    float s = pe[e];
    #pragma unroll
    for (int m=32;m>=1;m>>=1) s += __shfl_xor(s, m, 64);
    if (lane==0) sb8[e][wv] = s;
  }
  __syncthreads();
  if (t==0){
    float lg[8], mx = -1e30f;
    for (int e=0;e<8;e++){ lg[e] = sb8[e][0]+sb8[e][1]+sb8[e][2]+sb8[e][3] + rb[e]; mx = fmaxf(mx, lg[e]); }
    float ex[8], sum=0.f;
    for (int e=0;e<8;e++){ ex[e]=expf(lg[e]-mx); sum+=ex[e]; }
    float inv = 1.f/sum;
    int i0=0; float p0=-1.f;
    for (int e=0;e<8;e++){ float p=ex[e]*inv; if (p>p0){p0=p;i0=e;} }
    int i1=-1; float p1=-1.f;
    for (int e=0;e<8;e++){ if (e==i0) continue; float p=ex[e]*inv; if (p>p1){p1=p;i1=e;} }
    ti[2*tok]=i0; ti[2*tok+1]=i1; ts[2*tok]=p0; ts[2*tok+1]=p1;
  }
}

// ---------------- routing: bucket tokens by expert into 128-padded tiles ----------------
__global__ void route_build_k(const int* __restrict__ ti, const float* __restrict__ ts,
  int* __restrict__ slot_token, int* __restrict__ tok_slots, int* __restrict__ tile_expert)
{
  __shared__ int cnt[8], cur[8];
  int t = threadIdx.x;
  if (t < 8) cnt[t] = 0;
  __syncthreads();
  for (int tok = t; tok < NTOK; tok += 256){
    atomicAdd(&cnt[ti[2*tok]], 1);
    atomicAdd(&cnt[ti[2*tok+1]], 1);
  }
  __syncthreads();
  if (t == 0){
    int off = 0, tile = 0;
    for (int e=0;e<8;e++){
      cur[e] = off;
      int nt2 = (cnt[e] + 127) >> 7;
      for (int j=0;j<nt2;j++) tile_expert[tile++] = e;
      off += nt2 << 7;
    }
    while (tile < MAX_TILES) tile_expert[tile++] = -1;
  }
  __syncthreads();
  for (int i = t; i < SLOT_CAP; i += 256) slot_token[i] = -1;
  __syncthreads();
  for (int tok = t; tok < NTOK; tok += 256){
    #pragma unroll
    for (int j=0;j<2;j++){
      int e = ti[2*tok+j];
      int p = atomicAdd(&cur[e], 1);
      slot_token[p] = tok;
      tok_slots[2*tok+j] = p;
    }
  }
}

// ---------------- bf16 MFMA GEMM: C[128-tile M, 128-tile N] = A(bf16)[*,K] * B(f32)[N,K]^T ----------------
template<bool GATHER, bool EXPERT>
__global__ __launch_bounds__(256) void gemm_bf16k(
  const unsigned short* __restrict__ A, int lda,
  const int* __restrict__ slot_token,
  const float* __restrict__ B0, long long expert_stride,
  const int* __restrict__ tile_expert,
  float* __restrict__ C, int ldc, int K)
{
  int mt = blockIdx.y, nt = blockIdx.x;
  const float* Bp = B0;
  if (EXPERT){
    int e = tile_expert[mt];
    if (e < 0) return;
    Bp = B0 + (long long)e * expert_stride;
  }
  int m0 = mt*128, n0 = nt*128;
  __shared__ unsigned short As[128][40];
  __shared__ unsigned short Bs[128][40];
  int t = threadIdx.x;
  int w = t >> 6, lane = t & 63;
  int wm = (w >> 1) * 64, wn = (w & 1) * 64;
  int lr = lane & 15, quad = lane >> 4;
  f32x4 acc[4][4] = {};

  int arow = t >> 1;
  int ahalf = t & 1;
  const unsigned short* asrc = nullptr;
  bool avalid = true;
  if (GATHER){
    int tok = slot_token[m0 + arow];
    avalid = (tok >= 0);
    if (avalid) asrc = A + (size_t)tok * lda;
  } else {
    asrc = A + (size_t)(m0 + arow) * lda;
  }
  const float* bsrc = Bp + (size_t)(n0 + arow) * K;

  for (int k0 = 0; k0 < K; k0 += 32){
    uint4 av0 = make_uint4(0,0,0,0), av1 = make_uint4(0,0,0,0);
    if (avalid){
      const uint4* p = (const uint4*)(asrc + k0 + ahalf*16);
      av0 = p[0]; av1 = p[1];
    }
    const float4* q = (const float4*)(bsrc + k0 + ahalf*16);
    float4 b0 = q[0], b1 = q[1], b2 = q[2], b3 = q[3];
    uint4 w0, w1;
    w0.x = (uint32_t)f2bf(b0.x) | ((uint32_t)f2bf(b0.y)<<16);
    w0.y = (uint32_t)f2bf(b0.z) | ((uint32_t)f2bf(b0.w)<<16);
    w0.z = (uint32_t)f2bf(b1.x) | ((uint32_t)f2bf(b1.y)<<16);
    w0.w = (uint32_t)f2bf(b1.z) | ((uint32_t)f2bf(b1.w)<<16);
    w1.x = (uint32_t)f2bf(b2.x) | ((uint32_t)f2bf(b2.y)<<16);
    w1.y = (uint32_t)f2bf(b2.z) | ((uint32_t)f2bf(b2.w)<<16);
    w1.z = (uint32_t)f2bf(b3.x) | ((uint32_t)f2bf(b3.y)<<16);
    w1.w = (uint32_t)f2bf(b3.z) | ((uint32_t)f2bf(b3.w)<<16);
    __syncthreads();
    *(uint4*)&As[arow][ahalf*16]     = av0;
    *(uint4*)&As[arow][ahalf*16 + 8] = av1;
    *(uint4*)&Bs[arow][ahalf*16]     = w0;
    *(uint4*)&Bs[arow][ahalf*16 + 8] = w1;
    __syncthreads();
    short8 af[4], bf[4];
    #pragma unroll
    for (int mi=0;mi<4;mi++) af[mi] = *(const short8*)&As[wm + mi*16 + lr][quad*8];
    #pragma unroll
    for (int ni=0;ni<4;ni++) bf[ni] = *(const short8*)&Bs[wn + ni*16 + lr][quad*8];
    #pragma unroll
    for (int mi=0;mi<4;mi++)
      #pragma unroll
      for (int ni=0;ni<4;ni++)
        acc[mi][ni] = __builtin_amdgcn_mfma_f32_16x16x32_bf16(af[mi], bf[ni], acc[mi][ni], 0, 0, 0);
  }
  #pragma unroll
  for (int mi=0;mi<4;mi++){
    int rbase = m0 + wm + mi*16 + quad*4;
    #pragma unroll
    for (int ni=0;ni<4;ni++){
      int col = n0 + wn + ni*16 + lr;
      float* cp = C + (size_t)rbase*ldc + col;
      #pragma unroll
      for (int r=0;r<4;r++) cp[(size_t)r*ldc] = acc[mi][ni][r];
    }
  }
}

// ---------------- silu(h1a)*h1b -> hidden bf16 ----------------
__global__ __launch_bounds__(256) void silu_mul_k(
  const float* __restrict__ h1, unsigned short* __restrict__ hidden)
{
  int idx = blockIdx.x*256 + threadIdx.x;   // over SLOT_CAP*FFN
  int f = idx & (FFN-1); int slot = idx >> 11;
  float a = h1[(size_t)slot*2*FFN + f];
  float b = h1[(size_t)slot*2*FFN + FFN + f];
  hidden[idx] = f2bf(a*sigm(a)*b);
}

// ---------------- combine experts + final rms -> xnf bf16 ----------------
__global__ __launch_bounds__(256) void combine_rms_k(
  const float* __restrict__ x, const float* __restrict__ eo,
  const int* __restrict__ tok_slots, const float* __restrict__ ts,
  const float* __restrict__ fw, unsigned short* __restrict__ xnf)
{
  __shared__ float sb[4];
  int tok = blockIdx.x, t = threadIdx.x;
  int p0 = tok_slots[2*tok], p1 = tok_slots[2*tok+1];
  float s0 = ts[2*tok], s1 = ts[2*tok+1];
  float4 v  = *(const float4*)(x  + (size_t)tok*HD + t*4);
  float4 e0 = *(const float4*)(eo + (size_t)p0*HD + t*4);
  float4 e1 = *(const float4*)(eo + (size_t)p1*HD + t*4);
  v.x += s0*e0.x + s1*e1.x;
  v.y += s0*e0.y + s1*e1.y;
  v.z += s0*e0.z + s1*e1.z;
  v.w += s0*e0.w + s1*e1.w;
  float tot = block_sum(v.x*v.x+v.y*v.y+v.z*v.z+v.w*v.w, sb);
  float rs = rsqrtf(tot/(float)HD + EPSV);
  float4 w = *(const float4*)(fw + t*4);
  ushort4 o;
  o.x=f2bf(v.x*rs*w.x); o.y=f2bf(v.y*rs*w.y); o.z=f2bf(v.z*rs*w.z); o.w=f2bf(v.w*rs*w.w);
  *(ushort4*)(xnf + (size_t)tok*HD + t*4) = o;
}

extern "C" void kernel_launch(void* const* d_in, const int* in_sizes, int n_in,
                              void* d_out, int out_size, void* d_ws, size_t ws_size,
                              hipStream_t stream)
{
  const int*   ids  = (const int*)  d_in[0];
  const float* emb  = (const float*)d_in[1];
  const float* n0w  = (const float*)d_in[2];
  const float* ipw  = (const float*)d_in[3];
  const float* cw   = (const float*)d_in[4];
  const float* cb   = (const float*)d_in[5];
  const float* xpw  = (const float*)d_in[6];
  const float* dtw  = (const float*)d_in[7];
  const float* dtb  = (const float*)d_in[8];
  const float* alog = (const float*)d_in[9];
  const float* dpar = (const float*)d_in[10];
  const float* opw  = (const float*)d_in[11];
  const float* n1w  = (const float*)d_in[12];
  const float* rw   = (const float*)d_in[13];
  const float* rb   = (const float*)d_in[14];
  const float* f1w  = (const float*)d_in[15];
  const float* f2w  = (const float*)d_in[16];
  const float* fnw  = (const float*)d_in[17];
  float* out = (float*)d_out;
  char* ws = (char*)d_ws;

  // workspace layout (bytes); h1 overlays the dead proj..y span
  size_t o_x       = 0;                          // 8,388,608
  size_t o_xnbf    = o_x + 8388608;              // 4,194,304
  size_t o_ti      = o_xnbf + 4194304;           // 16,384
  size_t o_ts      = o_ti + 16384;               // 16,384
  size_t o_slott   = o_ts + 16384;               // 20,480
  size_t o_tslots  = o_slott + 20480;            // 16,384
  size_t o_tile    = o_tslots + 16384;           // 256
  size_t o_xn      = o_tile + 256;               // 8,388,608
  size_t o_proj    = o_xn + 8388608;             // 33,554,432
  size_t o_uconv   = o_proj + 33554432;          // 16,777,216
  size_t o_xp      = o_uconv + 16777216;         // 786,432
  size_t o_dl      = o_xp + 786432;              // 16,777,216
  size_t o_y       = o_dl + 16777216;            // 16,777,216
  size_t o_yg      = o_y + 16777216;             // 16,777,216
  size_t o_h1      = o_proj;                     // 83,886,080 (overlay, fits in proj..y span)
  size_t o_hidden  = o_yg + 16777216;            // 20,971,520
  size_t o_eo      = o_hidden + 20971520;        // 20,971,520
  size_t o_xnf     = o_eo + 20971520;            // 4,194,304
  // scan carry buffers overlay hidden/eo (dead until after scan): 3 x 8 MB
  size_t o_locfin  = o_hidden;                   // 8,388,608
  size_t o_pst     = o_locfin + 8388608;         // 8,388,608
  size_t o_init    = o_pst + 8388608;            // 8,388,608

  float* x      = (float*)(ws + o_x);
  unsigned short* xnbf = (unsigned short*)(ws + o_xnbf);
  int*   ti     = (int*)(ws + o_ti);
  float* ts     = (float*)(ws + o_ts);
  int*   slott  = (int*)(ws + o_slott);
  int*   tslots = (int*)(ws + o_tslots);
  int*   tile_e = (int*)(ws + o_tile);
  float* xn     = (float*)(ws + o_xn);
  float* proj   = (float*)(ws + o_proj);
  float* uconv  = (float*)(ws + o_uconv);
  float* xp     = (float*)(ws + o_xp);
  float* dl     = (float*)(ws + o_dl);
  float* y      = (float*)(ws + o_y);
  float* yg     = (float*)(ws + o_yg);
  float* h1     = (float*)(ws + o_h1);
  unsigned short* hidden = (unsigned short*)(ws + o_hidden);
  float* eo     = (float*)(ws + o_eo);
  unsigned short* xnf = (unsigned short*)(ws + o_xnf);
  float* locfin = (float*)(ws + o_locfin);
  float* pst    = (float*)(ws + o_pst);
  float* initst = (float*)(ws + o_init);

  embed_rms_k<<<NTOK,256,0,stream>>>(ids, emb, n0w, x, xn);
  // in_proj: [2048,1024] x [4096,1024]^T -> proj [2048,4096]
  gemm_f32k<0><<<dim3(64,32),256,0,stream>>>(xn, HD, ipw, proj, 4096, 4096, HD, nullptr);
  conv_silu_k<<<(NTOK*INNER)/256,256,0,stream>>>(proj, cw, cb, uconv);
  // x_proj: [2048,2048] x [96,2048]^T -> xp [2048,96]
  gemm_f32k<0><<<dim3(2,32),256,0,stream>>>(uconv, INNER, xpw, xp, 96, 96, INNER, nullptr);
  // dt_proj + bias + softplus: [2048,64(of 96)] x [2048,64]^T -> dl [2048,2048]
  gemm_f32k<1><<<dim3(32,32),256,0,stream>>>(xp, 96, dtw, dl, INNER, INNER, DTR, dtb);
  // chunked scan: 512 blocks (8 c-groups x 32 chunks x 2 batch)
  scan_p1<<<dim3(8,NCH,2),256,0,stream>>>(dl, uconv, xp, alog, locfin, pst);
  scan_p2<<<dim3(8,SDIM,2),256,0,stream>>>(locfin, pst, initst);
  scan_p3<<<dim3(8,NCH,2),256,0,stream>>>(dl, uconv, xp, alog, dpar, initst, y);
  ygate_k<<<(NTOK*INNER)/256,256,0,stream>>>(y, proj, yg);
  // out_proj + residual: [2048,2048] x [1024,2048]^T -> x += ...
  gemm_f32k<2><<<dim3(16,32),256,0,stream>>>(yg, INNER, opw, x, HD, HD, INNER, nullptr);
  rms_router_k<<<NTOK,256,0,stream>>>(x, n1w, rw, rb, xnbf, ti, ts);
  route_build_k<<<1,256,0,stream>>>(ti, ts, slott, tslots, tile_e);
  // fc1: gathered xn (bf16) x fc1_w[e] -> h1 [5120,4096]
  gemm_bf16k<true,true><<<dim3(32,MAX_TILES),256,0,stream>>>(
      xnbf, HD, slott, f1w, 4096LL*1024LL, tile_e, h1, 4096, HD);
  silu_mul_k<<<(SLOT_CAP*FFN)/256,256,0,stream>>>(h1, hidden);
  // fc2: hidden (bf16) x fc2_w[e] -> eo [5120,1024]
  gemm_bf16k<false,true><<<dim3(8,MAX_TILES),256,0,stream>>>(
      hidden, FFN, nullptr, f2w, 1024LL*2048LL, tile_e, eo, HD, FFN);
  combine_rms_k<<<NTOK,256,0,stream>>>(x, eo, tslots, ts, fnw, xnf);
  // LM head: xnf (bf16) x emb -> out [2048,32000]
  gemm_bf16k<false,false><<<dim3(VDIM/128,NTOK/128),256,0,stream>>>(
      xnf, HD, nullptr, emb, 0LL, nullptr, out, VDIM, HD);
}